// Round 3
// baseline (9409.431 us; speedup 1.0000x reference)
//
#include <hip/hip_runtime.h>
#include <hip/hip_bf16.h>
#include <cstdint>

typedef unsigned short ushort_t;
typedef __attribute__((ext_vector_type(8))) short short8;
typedef __attribute__((ext_vector_type(4))) float floatx4;
typedef __attribute__((ext_vector_type(4))) ushort_t ushort4v;

#define DEVI __device__ __forceinline__

DEVI float b2f(ushort_t u){ union{unsigned int i; float f;} v; v.i = ((unsigned int)u)<<16; return v.f; }
DEVI ushort_t f2b(float f){ union{float f; unsigned int i;} v; v.f=f; unsigned int r = (v.i + 0x7FFFu + ((v.i>>16)&1u)) >> 16; return (ushort_t)r; }

DEVI float gelu_f(float t){
  float t3 = t*t*t;
  return 0.5f*t*(1.0f + tanhf(0.7978845608028654f*(t + 0.044715f*t3)));
}

#define GLD_LDS16(src, dst) \
  __builtin_amdgcn_global_load_lds((const __attribute__((address_space(1))) void*)(src), \
                                   (__attribute__((address_space(3))) void*)(dst), 16, 0, 0)

// ---------------------------------------------------------------------------
// GEMM 128x128 tile, BK=32, kc-major LDS layout [4 kc][128 row][8] (bank-conflict-free:
// fragment ds_read_b128 walks consecutive rows -> 16B stride -> all 32 banks, 2-way = free).
// global_load_lds writes slot c = lane-linear; source address swizzled so slot c holds
// (row=c&127, kc=c>>7).
// out[M,N](bf16) = epi(A[M,K](bf16) @ Bt[N,K]^T + bias(fp32) [, res(fp32)])
// EPI: 0 = elu(v)+1, 1 = v, 2 = gelu(v), 3 = gelu(v)+res
// ---------------------------------------------------------------------------
template<int EPI>
__global__ __launch_bounds__(256)
void gemm_kernel(const ushort_t* __restrict__ A, const ushort_t* __restrict__ Bt,
                 const float* __restrict__ bias, const float* __restrict__ res,
                 ushort_t* __restrict__ out, int N, int K)
{
  __shared__ alignas(16) ushort_t As[4096];
  __shared__ alignas(16) ushort_t Bs[4096];
  const int tid  = threadIdx.x;
  const int wave = tid >> 6, lane = tid & 63;
  const int quad = lane >> 4, l16 = lane & 15;
  const int tileM = blockIdx.x * 128, tileN = blockIdx.y * 128;
  const int wm = (wave >> 1) * 64, wn = (wave & 1) * 64;

  floatx4 acc[4][4] = {};

  const int c0 = tid, c1 = 256 + tid;   // LDS slot c: row = c&127, kc = c>>7
  const size_t aoff0 = (size_t)(tileM + (c0 & 127)) * K + (c0 >> 7) * 8;
  const size_t aoff1 = (size_t)(tileM + (c1 & 127)) * K + (c1 >> 7) * 8;
  const size_t boff0 = (size_t)(tileN + (c0 & 127)) * K + (c0 >> 7) * 8;
  const size_t boff1 = (size_t)(tileN + (c1 & 127)) * K + (c1 >> 7) * 8;

  for (int k0 = 0; k0 < K; k0 += 32){
    __syncthreads();
    GLD_LDS16(A  + aoff0 + k0, As + wave*512);
    GLD_LDS16(A  + aoff1 + k0, As + 2048 + wave*512);
    GLD_LDS16(Bt + boff0 + k0, Bs + wave*512);
    GLD_LDS16(Bt + boff1 + k0, Bs + 2048 + wave*512);
    __syncthreads();

    short8 af[4], bfv[4];
    #pragma unroll
    for (int i = 0; i < 4; i++){
      af[i]  = *(const short8*)(As + quad*1024 + (wm + i*16 + l16)*8);
      bfv[i] = *(const short8*)(Bs + quad*1024 + (wn + i*16 + l16)*8);
    }
    #pragma unroll
    for (int mi = 0; mi < 4; mi++)
      #pragma unroll
      for (int ni = 0; ni < 4; ni++)
        acc[mi][ni] = __builtin_amdgcn_mfma_f32_16x16x32_bf16(af[mi], bfv[ni], acc[mi][ni], 0, 0, 0);
  }

  float bv4[4];
  #pragma unroll
  for (int ni = 0; ni < 4; ni++) bv4[ni] = bias[tileN + wn + ni*16 + l16];

  #pragma unroll
  for (int mi = 0; mi < 4; mi++){
    #pragma unroll
    for (int r = 0; r < 4; r++){
      const int row = tileM + wm + mi*16 + quad*4 + r;
      #pragma unroll
      for (int ni = 0; ni < 4; ni++){
        const int col = tileN + wn + ni*16 + l16;
        float v = acc[mi][ni][r] + bv4[ni];
        if constexpr (EPI == 0){ v = (v > 0.f) ? (v + 1.f) : expf(v); }
        else if constexpr (EPI == 2){ v = gelu_f(v); }
        else if constexpr (EPI == 3){ v = gelu_f(v) + res[(size_t)row*N + col]; }
        out[(size_t)row*N + col] = f2b(v);
      }
    }
  }
}

// ---------------------------------------------------------------------------
// Fused QKV GEMM: Bt = [WqT;WkT;WvT] (3072 x K). Per-block segment decides
// output buffer + bias + epilogue (seg<2: elu+1; seg==2: identity).
// ---------------------------------------------------------------------------
__global__ __launch_bounds__(256)
void qkv_gemm_kernel(const ushort_t* __restrict__ A, const ushort_t* __restrict__ Bt,
                     const float* __restrict__ bq, const float* __restrict__ bk,
                     const float* __restrict__ bv,
                     ushort_t* __restrict__ outQ, ushort_t* __restrict__ outK,
                     ushort_t* __restrict__ outV, int K)
{
  __shared__ alignas(16) ushort_t As[4096];
  __shared__ alignas(16) ushort_t Bs[4096];
  const int tid  = threadIdx.x;
  const int wave = tid >> 6, lane = tid & 63;
  const int quad = lane >> 4, l16 = lane & 15;
  const int tileM = blockIdx.x * 128, tileN = blockIdx.y * 128;
  const int wm = (wave >> 1) * 64, wn = (wave & 1) * 64;

  const int seg = tileN >> 10;                 // 0=Q, 1=K, 2=V
  const int nloc = tileN & 1023;
  const float* bias = (seg == 0) ? bq : (seg == 1) ? bk : bv;
  ushort_t* out     = (seg == 0) ? outQ : (seg == 1) ? outK : outV;

  floatx4 acc[4][4] = {};

  const int c0 = tid, c1 = 256 + tid;
  const size_t aoff0 = (size_t)(tileM + (c0 & 127)) * K + (c0 >> 7) * 8;
  const size_t aoff1 = (size_t)(tileM + (c1 & 127)) * K + (c1 >> 7) * 8;
  const size_t boff0 = (size_t)(tileN + (c0 & 127)) * K + (c0 >> 7) * 8;
  const size_t boff1 = (size_t)(tileN + (c1 & 127)) * K + (c1 >> 7) * 8;

  for (int k0 = 0; k0 < K; k0 += 32){
    __syncthreads();
    GLD_LDS16(A  + aoff0 + k0, As + wave*512);
    GLD_LDS16(A  + aoff1 + k0, As + 2048 + wave*512);
    GLD_LDS16(Bt + boff0 + k0, Bs + wave*512);
    GLD_LDS16(Bt + boff1 + k0, Bs + 2048 + wave*512);
    __syncthreads();

    short8 af[4], bfv[4];
    #pragma unroll
    for (int i = 0; i < 4; i++){
      af[i]  = *(const short8*)(As + quad*1024 + (wm + i*16 + l16)*8);
      bfv[i] = *(const short8*)(Bs + quad*1024 + (wn + i*16 + l16)*8);
    }
    #pragma unroll
    for (int mi = 0; mi < 4; mi++)
      #pragma unroll
      for (int ni = 0; ni < 4; ni++)
        acc[mi][ni] = __builtin_amdgcn_mfma_f32_16x16x32_bf16(af[mi], bfv[ni], acc[mi][ni], 0, 0, 0);
  }

  float bv4[4];
  #pragma unroll
  for (int ni = 0; ni < 4; ni++) bv4[ni] = bias[nloc + wn + ni*16 + l16];

  #pragma unroll
  for (int mi = 0; mi < 4; mi++){
    #pragma unroll
    for (int r = 0; r < 4; r++){
      const int row = tileM + wm + mi*16 + quad*4 + r;
      #pragma unroll
      for (int ni = 0; ni < 4; ni++){
        const int col = nloc + wn + ni*16 + l16;
        float v = acc[mi][ni][r] + bv4[ni];
        if (seg < 2){ v = (v > 0.f) ? (v + 1.f) : expf(v); }
        out[(size_t)row*1024 + col] = f2b(v);
      }
    }
  }
}

// KV[b,h] = sum_s K*V; Ksum[b,h] = sum_s K  (bf16 in, fp32 atomics)
__global__ __launch_bounds__(256)
void reduce_kv_kernel(const ushort_t* __restrict__ Kb, const ushort_t* __restrict__ Vb,
                      float* __restrict__ KV, float* __restrict__ Ksum)
{
  const int b = blockIdx.x >> 6, chunk = blockIdx.x & 63;
  const int t = threadIdx.x;
  const size_t base = ((size_t)b*4096 + (size_t)chunk*64)*1024 + t*4;
  float kv[4] = {0,0,0,0}, ks[4] = {0,0,0,0};
  for (int s = 0; s < 64; s++){
    ushort4v kk = *(const ushort4v*)(Kb + base + (size_t)s*1024);
    ushort4v vv = *(const ushort4v*)(Vb + base + (size_t)s*1024);
    #pragma unroll
    for (int j = 0; j < 4; j++){ float kf = b2f(kk[j]); kv[j] += kf*b2f(vv[j]); ks[j] += kf; }
  }
  #pragma unroll
  for (int j = 0; j < 4; j++){
    atomicAdd(&KV[b*1024 + t*4 + j], kv[j]);
    atomicAdd(&Ksum[b*1024 + t*4 + j], ks[j]);
  }
}

// Q <- Q*KV / (Q*Ksum + eps), in place (bf16)
__global__ __launch_bounds__(256)
void attn_map_kernel(ushort_t* __restrict__ Q, const float* __restrict__ KV, const float* __restrict__ Ksum)
{
  const size_t g = (size_t)blockIdx.x*256 + threadIdx.x;
  const size_t base = g*4;
  const int b  = (int)(base >> 22);
  const int h0 = (int)(base & 1023);
  ushort4v q4 = *(const ushort4v*)(Q + base);
  ushort4v o4;
  #pragma unroll
  for (int j = 0; j < 4; j++){
    float q = b2f(q4[j]);
    float v = q*KV[b*1024 + h0 + j] / (q*Ksum[b*1024 + h0 + j] + 1e-6f);
    o4[j] = f2b(v);
  }
  *(ushort4v*)(Q + base) = o4;
}

// LayerNorm rows of 1024: y(bf16) -> xb(bf16) AND xf(fp32)
__global__ __launch_bounds__(256)
void ln_kernel(const ushort_t* __restrict__ y, const float* __restrict__ sc,
               const float* __restrict__ bi, ushort_t* __restrict__ xb, float* __restrict__ xf)
{
  const int row = blockIdx.x, t = threadIdx.x;
  const ushort_t* yr = y + (size_t)row*1024;
  ushort4v v4 = *(const ushort4v*)(yr + t*4);
  float f[4]; float s1 = 0.f, s2 = 0.f;
  #pragma unroll
  for (int j = 0; j < 4; j++){ f[j] = b2f(v4[j]); s1 += f[j]; s2 += f[j]*f[j]; }
  #pragma unroll
  for (int off = 32; off; off >>= 1){ s1 += __shfl_down(s1, off); s2 += __shfl_down(s2, off); }
  __shared__ float red[2][4];
  const int wave = t >> 6, lane = t & 63;
  if (lane == 0){ red[0][wave] = s1; red[1][wave] = s2; }
  __syncthreads();
  s1 = red[0][0] + red[0][1] + red[0][2] + red[0][3];
  s2 = red[1][0] + red[1][1] + red[1][2] + red[1][3];
  const float mean = s1 * (1.0f/1024.0f);
  const float var  = s2 * (1.0f/1024.0f) - mean*mean;
  const float inv  = rsqrtf(var + 1e-6f);
  ushort4v o4;
  #pragma unroll
  for (int j = 0; j < 4; j++){
    const int h = t*4 + j;
    const float o = (f[j] - mean)*inv*sc[h] + bi[h];
    o4[j] = f2b(o);
    xf[(size_t)row*1024 + h] = o;
  }
  *(ushort4v*)(xb + (size_t)row*1024 + t*4) = o4;
}

// ---------------------------------------------------------------------------
// Fused per-block weight transpose+convert: 6 matrices in one dispatch.
// ids [0,4096): W1 (1024x4096, nx=128), [4096,8192): W2 (4096x1024, nx=32),
// [8192,12288): Wq/Wk/Wv/Wo (1024x1024, nx=32).
// ---------------------------------------------------------------------------
struct TParams { const float* src[6]; ushort_t* dst[6]; };

__global__ __launch_bounds__(256)
void transpose_all_kernel(TParams p)
{
  __shared__ float tile[32][33];
  const int id = blockIdx.x;
  int m, bx, by, R, C;
  if (id < 4096){ m = 4; int l = id;        bx = l & 127; by = l >> 7; R = 1024; C = 4096; }
  else if (id < 8192){ m = 5; int l = id - 4096; bx = l & 31; by = l >> 5; R = 4096; C = 1024; }
  else { int l = id - 8192; m = l >> 10; l &= 1023; bx = l & 31; by = l >> 5; R = 1024; C = 1024; }
  const float* in = p.src[m];
  ushort_t* out = p.dst[m];
  const int t = threadIdx.x;
  const int tx = t & 31, ty = t >> 5;
  const int rb = by*32, cb = bx*32;
  #pragma unroll
  for (int j = 0; j < 32; j += 8) tile[ty+j][tx] = in[(size_t)(rb+ty+j)*C + cb+tx];
  __syncthreads();
  #pragma unroll
  for (int j = 0; j < 32; j += 8) out[(size_t)(cb+ty+j)*R + rb+tx] = f2b(tile[tx][ty+j]);
}

// bf16 copy of fp32 input
__global__ __launch_bounds__(256)
void cvt_kernel(const float* __restrict__ in, ushort_t* __restrict__ out)
{
  const size_t base = ((size_t)blockIdx.x*256 + threadIdx.x)*4;
  ushort4v o4;
  #pragma unroll
  for (int j = 0; j < 4; j++) o4[j] = f2b(in[base + j]);
  *(ushort4v*)(out + base) = o4;
}

extern "C" void kernel_launch(void* const* d_in, const int* in_sizes, int n_in,
                              void* d_out, int out_size, void* d_ws, size_t ws_size,
                              hipStream_t stream)
{
  const float* x_in = (const float*)d_in[0];
  const float* Wq   = (const float*)d_in[1];
  const float* bq   = (const float*)d_in[2];
  const float* Wk   = (const float*)d_in[3];
  const float* bk   = (const float*)d_in[4];
  const float* Wv   = (const float*)d_in[5];
  const float* bv   = (const float*)d_in[6];
  const float* Wo   = (const float*)d_in[7];
  const float* bo   = (const float*)d_in[8];
  const float* ln1s = (const float*)d_in[9];
  const float* ln1b = (const float*)d_in[10];
  const float* W1   = (const float*)d_in[11];
  const float* b1   = (const float*)d_in[12];
  const float* W2   = (const float*)d_in[13];
  const float* b2   = (const float*)d_in[14];
  const float* ln2s = (const float*)d_in[15];
  const float* ln2b = (const float*)d_in[16];

  float* xf = (float*)d_out;            // fp32 master activation (also final output)

  char* ws = (char*)d_ws;
  const size_t MB = 1024*1024;
  ushort_t* xb     = (ushort_t*)(ws);              // 32MB bf16 activation
  char*     regB   = ws + 32*MB;                   // 160MB aliased region
  ushort_t* bufQ   = (ushort_t*)(regB);            // attn: 32MB Q -> V_attn
  ushort_t* bufK   = (ushort_t*)(regB + 32*MB);    // attn: 32MB K
  ushort_t* bufVal = (ushort_t*)(regB + 64*MB);    // attn: 32MB value -> pre-LN y
  ushort_t* bufH   = (ushort_t*)(regB);            // ff:   128MB hidden (stomps Q/K/Val)
  ushort_t* bufY   = (ushort_t*)(regB + 128*MB);   // ff:   32MB pre-LN y
  ushort_t* WqkvT  = (ushort_t*)(ws + 192*MB);     // 6MB [3072][1024]
  ushort_t* WoT    = (ushort_t*)(ws + 198*MB);     // 2MB
  ushort_t* W1T    = (ushort_t*)(ws + 200*MB);     // 8MB [4096][1024]
  ushort_t* W2T    = (ushort_t*)(ws + 208*MB);     // 8MB [1024][4096]
  float*    KV     = (float*)(ws + 216*MB);        // 16KB
  float*    Ksum   = (float*)(ws + 216*MB + 16*1024);

  const int M = 16384, D = 1024, FF = 4096;
  const dim3 blk(256);

  hipMemcpyAsync(xf, x_in, (size_t)M*D*sizeof(float), hipMemcpyDeviceToDevice, stream);
  cvt_kernel<<<dim3(M*D/1024), blk, 0, stream>>>(x_in, xb);

  for (int i = 0; i < 8; i++){
    TParams tp;
    tp.src[0] = Wq + (size_t)i*D*D;  tp.dst[0] = WqkvT;
    tp.src[1] = Wk + (size_t)i*D*D;  tp.dst[1] = WqkvT + 1024*1024;
    tp.src[2] = Wv + (size_t)i*D*D;  tp.dst[2] = WqkvT + 2*1024*1024;
    tp.src[3] = Wo + (size_t)i*D*D;  tp.dst[3] = WoT;
    tp.src[4] = W1 + (size_t)i*D*FF; tp.dst[4] = W1T;
    tp.src[5] = W2 + (size_t)i*FF*D; tp.dst[5] = W2T;
    transpose_all_kernel<<<dim3(12288), blk, 0, stream>>>(tp);

    // Q = elu(x@Wq+bq)+1 ; K = elu(x@Wk+bk)+1 ; value = x@Wv+bv  (one fused GEMM)
    qkv_gemm_kernel<<<dim3(128, 24), blk, 0, stream>>>(xb, WqkvT, bq + i*D, bk + i*D, bv + i*D,
                                                       bufQ, bufK, bufVal, D);

    hipMemsetAsync(KV, 0, 32*1024, stream);
    reduce_kv_kernel<<<dim3(256), blk, 0, stream>>>(bufK, bufVal, KV, Ksum);
    attn_map_kernel<<<dim3(16384), blk, 0, stream>>>(bufQ, KV, Ksum);

    // y = gelu(V_attn@Wo + bo) + x ; x = LN1(y)
    gemm_kernel<3><<<dim3(128, 8), blk, 0, stream>>>(bufQ, WoT, bo + i*D, xf, bufVal, D, D);
    ln_kernel<<<dim3(16384), blk, 0, stream>>>(bufVal, ln1s + i*D, ln1b + i*D, xb, xf);

    // h = gelu(x@W1 + b1) ; y = gelu(h@W2 + b2) + x ; x = LN2(y)   (full M)
    gemm_kernel<2><<<dim3(128, 32), blk, 0, stream>>>(xb, W1T, b1 + i*FF, nullptr, bufH, FF, D);
    gemm_kernel<3><<<dim3(128, 8),  blk, 0, stream>>>(bufH, W2T, b2 + i*D, xf, bufY, D, FF);
    ln_kernel<<<dim3(16384), blk, 0, stream>>>(bufY, ln2s + i*D, ln2b + i*D, xb, xf);
  }
  (void)in_sizes; (void)n_in; (void)out_size; (void)ws_size;
}

// Round 4
// 6652.641 us; speedup vs baseline: 1.4144x; 1.4144x over previous
//
#include <hip/hip_runtime.h>
#include <hip/hip_bf16.h>
#include <cstdint>

typedef unsigned short ushort_t;
typedef __attribute__((ext_vector_type(8))) short short8;
typedef __attribute__((ext_vector_type(4))) float floatx4;
typedef __attribute__((ext_vector_type(4))) ushort_t ushort4v;

#define DEVI __device__ __forceinline__

DEVI float b2f(ushort_t u){ union{unsigned int i; float f;} v; v.i = ((unsigned int)u)<<16; return v.f; }
DEVI ushort_t f2b(float f){ union{float f; unsigned int i;} v; v.f=f; unsigned int r = (v.i + 0x7FFFu + ((v.i>>16)&1u)) >> 16; return (ushort_t)r; }

DEVI float gelu_f(float t){
  float t3 = t*t*t;
  return 0.5f*t*(1.0f + tanhf(0.7978845608028654f*(t + 0.044715f*t3)));
}

#define GLD_LDS16(src, dst) \
  __builtin_amdgcn_global_load_lds((const __attribute__((address_space(1))) void*)(src), \
                                   (__attribute__((address_space(3))) void*)(dst), 16, 0, 0)

// ---------------------------------------------------------------------------
// GEMM 128x128 tile, BK=32, double-buffered LDS, XOR-swizzled layout:
//   granule (row r, kc) stored at slot r*4 + (kc ^ (r&3)).
//   - staging: slot c holds (r=c>>2, kc=(c&3)^(r&3)); 4 consecutive lanes still
//     cover one contiguous 64B row chunk -> coalesced global_load_lds.
//   - frag read: ds_read_b128 spreads 16 lanes over 4 bank groups (4-way).
// K-loop: one barrier per iter; GLD(k+1) issued before tile-k compute so the
// load is in flight during ds_read+MFMA and drained at the next barrier.
// out[M,N](bf16) = epi(A[M,K](bf16) @ Bt[N,K]^T + bias(fp32) [, res(fp32)])
// EPI: 0 = elu(v)+1, 1 = v, 2 = gelu(v), 3 = gelu(v)+res
// ---------------------------------------------------------------------------
template<int EPI>
__global__ __launch_bounds__(256)
void gemm_kernel(const ushort_t* __restrict__ A, const ushort_t* __restrict__ Bt,
                 const float* __restrict__ bias, const float* __restrict__ res,
                 ushort_t* __restrict__ out, int N, int K)
{
  __shared__ alignas(16) ushort_t As[2][4096];
  __shared__ alignas(16) ushort_t Bs[2][4096];
  const int tid  = threadIdx.x;
  const int wave = tid >> 6, lane = tid & 63;
  const int quad = lane >> 4, l16 = lane & 15;
  const int tileM = blockIdx.x * 128, tileN = blockIdx.y * 128;
  const int wm = (wave >> 1) * 64, wn = (wave & 1) * 64;
  const int sw = quad ^ (l16 & 3);          // frag-read slot swizzle (wm,wn,i are mult of 16)

  floatx4 acc[4][4] = {};

  // staging source offsets: slot c -> row r=c>>2, k-chunk kd=(c&3)^(r&3)
  const int r0 = tid >> 2,        kd0 = (tid & 3) ^ (r0 & 3);
  const int r1 = (256+tid) >> 2,  kd1 = ((256+tid) & 3) ^ (r1 & 3);
  const size_t aoff0 = (size_t)(tileM + r0) * K + kd0 * 8;
  const size_t aoff1 = (size_t)(tileM + r1) * K + kd1 * 8;
  const size_t boff0 = (size_t)(tileN + r0) * K + kd0 * 8;
  const size_t boff1 = (size_t)(tileN + r1) * K + kd1 * 8;

  // prologue: tile 0 -> buffer 0
  GLD_LDS16(A  + aoff0, &As[0][0] + wave*512);
  GLD_LDS16(A  + aoff1, &As[0][0] + 2048 + wave*512);
  GLD_LDS16(Bt + boff0, &Bs[0][0] + wave*512);
  GLD_LDS16(Bt + boff1, &Bs[0][0] + 2048 + wave*512);

  const int nIter = K >> 5;
  for (int it = 0; it < nIter; ++it){
    const int cur = it & 1, nxt = cur ^ 1;
    __syncthreads();   // drains GLD(cur) (vmcnt0) + fences all reads of buf[nxt] from it-1
    if (it + 1 < nIter){
      const size_t k8 = (size_t)(it + 1) * 32;
      GLD_LDS16(A  + aoff0 + k8, &As[nxt][0] + wave*512);
      GLD_LDS16(A  + aoff1 + k8, &As[nxt][0] + 2048 + wave*512);
      GLD_LDS16(Bt + boff0 + k8, &Bs[nxt][0] + wave*512);
      GLD_LDS16(Bt + boff1 + k8, &Bs[nxt][0] + 2048 + wave*512);
    }
    short8 af[4], bfv[4];
    #pragma unroll
    for (int i = 0; i < 4; i++){
      af[i]  = *(const short8*)(&As[cur][0] + ((wm + i*16 + l16)*4 + sw)*8);
      bfv[i] = *(const short8*)(&Bs[cur][0] + ((wn + i*16 + l16)*4 + sw)*8);
    }
    #pragma unroll
    for (int mi = 0; mi < 4; mi++)
      #pragma unroll
      for (int ni = 0; ni < 4; ni++)
        acc[mi][ni] = __builtin_amdgcn_mfma_f32_16x16x32_bf16(af[mi], bfv[ni], acc[mi][ni], 0, 0, 0);
  }

  float bv4[4];
  #pragma unroll
  for (int ni = 0; ni < 4; ni++) bv4[ni] = bias[tileN + wn + ni*16 + l16];

  #pragma unroll
  for (int mi = 0; mi < 4; mi++){
    #pragma unroll
    for (int r = 0; r < 4; r++){
      const int row = tileM + wm + mi*16 + quad*4 + r;
      #pragma unroll
      for (int ni = 0; ni < 4; ni++){
        const int col = tileN + wn + ni*16 + l16;
        float v = acc[mi][ni][r] + bv4[ni];
        if constexpr (EPI == 0){ v = (v > 0.f) ? (v + 1.f) : expf(v); }
        else if constexpr (EPI == 2){ v = gelu_f(v); }
        else if constexpr (EPI == 3){ v = gelu_f(v) + res[(size_t)row*N + col]; }
        out[(size_t)row*N + col] = f2b(v);
      }
    }
  }
}

// ---------------------------------------------------------------------------
// Fused QKV GEMM: Bt = [WqT;WkT;WvT] (3072 x K), same core as gemm_kernel.
// ---------------------------------------------------------------------------
__global__ __launch_bounds__(256)
void qkv_gemm_kernel(const ushort_t* __restrict__ A, const ushort_t* __restrict__ Bt,
                     const float* __restrict__ bq, const float* __restrict__ bk,
                     const float* __restrict__ bv,
                     ushort_t* __restrict__ outQ, ushort_t* __restrict__ outK,
                     ushort_t* __restrict__ outV, int K)
{
  __shared__ alignas(16) ushort_t As[2][4096];
  __shared__ alignas(16) ushort_t Bs[2][4096];
  const int tid  = threadIdx.x;
  const int wave = tid >> 6, lane = tid & 63;
  const int quad = lane >> 4, l16 = lane & 15;
  const int tileM = blockIdx.x * 128, tileN = blockIdx.y * 128;
  const int wm = (wave >> 1) * 64, wn = (wave & 1) * 64;
  const int sw = quad ^ (l16 & 3);

  const int seg = tileN >> 10;                 // 0=Q, 1=K, 2=V
  const int nloc = tileN & 1023;
  const float* bias = (seg == 0) ? bq : (seg == 1) ? bk : bv;
  ushort_t* out     = (seg == 0) ? outQ : (seg == 1) ? outK : outV;

  floatx4 acc[4][4] = {};

  const int r0 = tid >> 2,        kd0 = (tid & 3) ^ (r0 & 3);
  const int r1 = (256+tid) >> 2,  kd1 = ((256+tid) & 3) ^ (r1 & 3);
  const size_t aoff0 = (size_t)(tileM + r0) * K + kd0 * 8;
  const size_t aoff1 = (size_t)(tileM + r1) * K + kd1 * 8;
  const size_t boff0 = (size_t)(tileN + r0) * K + kd0 * 8;
  const size_t boff1 = (size_t)(tileN + r1) * K + kd1 * 8;

  GLD_LDS16(A  + aoff0, &As[0][0] + wave*512);
  GLD_LDS16(A  + aoff1, &As[0][0] + 2048 + wave*512);
  GLD_LDS16(Bt + boff0, &Bs[0][0] + wave*512);
  GLD_LDS16(Bt + boff1, &Bs[0][0] + 2048 + wave*512);

  const int nIter = K >> 5;
  for (int it = 0; it < nIter; ++it){
    const int cur = it & 1, nxt = cur ^ 1;
    __syncthreads();
    if (it + 1 < nIter){
      const size_t k8 = (size_t)(it + 1) * 32;
      GLD_LDS16(A  + aoff0 + k8, &As[nxt][0] + wave*512);
      GLD_LDS16(A  + aoff1 + k8, &As[nxt][0] + 2048 + wave*512);
      GLD_LDS16(Bt + boff0 + k8, &Bs[nxt][0] + wave*512);
      GLD_LDS16(Bt + boff1 + k8, &Bs[nxt][0] + 2048 + wave*512);
    }
    short8 af[4], bfv[4];
    #pragma unroll
    for (int i = 0; i < 4; i++){
      af[i]  = *(const short8*)(&As[cur][0] + ((wm + i*16 + l16)*4 + sw)*8);
      bfv[i] = *(const short8*)(&Bs[cur][0] + ((wn + i*16 + l16)*4 + sw)*8);
    }
    #pragma unroll
    for (int mi = 0; mi < 4; mi++)
      #pragma unroll
      for (int ni = 0; ni < 4; ni++)
        acc[mi][ni] = __builtin_amdgcn_mfma_f32_16x16x32_bf16(af[mi], bfv[ni], acc[mi][ni], 0, 0, 0);
  }

  float bv4[4];
  #pragma unroll
  for (int ni = 0; ni < 4; ni++) bv4[ni] = bias[nloc + wn + ni*16 + l16];

  #pragma unroll
  for (int mi = 0; mi < 4; mi++){
    #pragma unroll
    for (int r = 0; r < 4; r++){
      const int row = tileM + wm + mi*16 + quad*4 + r;
      #pragma unroll
      for (int ni = 0; ni < 4; ni++){
        const int col = nloc + wn + ni*16 + l16;
        float v = acc[mi][ni][r] + bv4[ni];
        if (seg < 2){ v = (v > 0.f) ? (v + 1.f) : expf(v); }
        out[(size_t)row*1024 + col] = f2b(v);
      }
    }
  }
}

// KV[b,h] = sum_s K*V; Ksum[b,h] = sum_s K  (bf16 in, fp32 atomics)
__global__ __launch_bounds__(256)
void reduce_kv_kernel(const ushort_t* __restrict__ Kb, const ushort_t* __restrict__ Vb,
                      float* __restrict__ KV, float* __restrict__ Ksum)
{
  const int b = blockIdx.x >> 6, chunk = blockIdx.x & 63;
  const int t = threadIdx.x;
  const size_t base = ((size_t)b*4096 + (size_t)chunk*64)*1024 + t*4;
  float kv[4] = {0,0,0,0}, ks[4] = {0,0,0,0};
  for (int s = 0; s < 64; s++){
    ushort4v kk = *(const ushort4v*)(Kb + base + (size_t)s*1024);
    ushort4v vv = *(const ushort4v*)(Vb + base + (size_t)s*1024);
    #pragma unroll
    for (int j = 0; j < 4; j++){ float kf = b2f(kk[j]); kv[j] += kf*b2f(vv[j]); ks[j] += kf; }
  }
  #pragma unroll
  for (int j = 0; j < 4; j++){
    atomicAdd(&KV[b*1024 + t*4 + j], kv[j]);
    atomicAdd(&Ksum[b*1024 + t*4 + j], ks[j]);
  }
}

// Q <- Q*KV / (Q*Ksum + eps), in place (bf16)
__global__ __launch_bounds__(256)
void attn_map_kernel(ushort_t* __restrict__ Q, const float* __restrict__ KV, const float* __restrict__ Ksum)
{
  const size_t g = (size_t)blockIdx.x*256 + threadIdx.x;
  const size_t base = g*4;
  const int b  = (int)(base >> 22);
  const int h0 = (int)(base & 1023);
  ushort4v q4 = *(const ushort4v*)(Q + base);
  ushort4v o4;
  #pragma unroll
  for (int j = 0; j < 4; j++){
    float q = b2f(q4[j]);
    float v = q*KV[b*1024 + h0 + j] / (q*Ksum[b*1024 + h0 + j] + 1e-6f);
    o4[j] = f2b(v);
  }
  *(ushort4v*)(Q + base) = o4;
}

// LayerNorm rows of 1024: y(bf16) -> xb(bf16) AND xf(fp32)
__global__ __launch_bounds__(256)
void ln_kernel(const ushort_t* __restrict__ y, const float* __restrict__ sc,
               const float* __restrict__ bi, ushort_t* __restrict__ xb, float* __restrict__ xf)
{
  const int row = blockIdx.x, t = threadIdx.x;
  const ushort_t* yr = y + (size_t)row*1024;
  ushort4v v4 = *(const ushort4v*)(yr + t*4);
  float f[4]; float s1 = 0.f, s2 = 0.f;
  #pragma unroll
  for (int j = 0; j < 4; j++){ f[j] = b2f(v4[j]); s1 += f[j]; s2 += f[j]*f[j]; }
  #pragma unroll
  for (int off = 32; off; off >>= 1){ s1 += __shfl_down(s1, off); s2 += __shfl_down(s2, off); }
  __shared__ float red[2][4];
  const int wave = t >> 6, lane = t & 63;
  if (lane == 0){ red[0][wave] = s1; red[1][wave] = s2; }
  __syncthreads();
  s1 = red[0][0] + red[0][1] + red[0][2] + red[0][3];
  s2 = red[1][0] + red[1][1] + red[1][2] + red[1][3];
  const float mean = s1 * (1.0f/1024.0f);
  const float var  = s2 * (1.0f/1024.0f) - mean*mean;
  const float inv  = rsqrtf(var + 1e-6f);
  ushort4v o4;
  #pragma unroll
  for (int j = 0; j < 4; j++){
    const int h = t*4 + j;
    const float o = (f[j] - mean)*inv*sc[h] + bi[h];
    o4[j] = f2b(o);
    xf[(size_t)row*1024 + h] = o;
  }
  *(ushort4v*)(xb + (size_t)row*1024 + t*4) = o4;
}

// ---------------------------------------------------------------------------
// Fused per-block weight transpose+convert: 6 matrices in one dispatch.
// ---------------------------------------------------------------------------
struct TParams { const float* src[6]; ushort_t* dst[6]; };

__global__ __launch_bounds__(256)
void transpose_all_kernel(TParams p)
{
  __shared__ float tile[32][33];
  const int id = blockIdx.x;
  int m, bx, by, R, C;
  if (id < 4096){ m = 4; int l = id;        bx = l & 127; by = l >> 7; R = 1024; C = 4096; }
  else if (id < 8192){ m = 5; int l = id - 4096; bx = l & 31; by = l >> 5; R = 4096; C = 1024; }
  else { int l = id - 8192; m = l >> 10; l &= 1023; bx = l & 31; by = l >> 5; R = 1024; C = 1024; }
  const float* in = p.src[m];
  ushort_t* out = p.dst[m];
  const int t = threadIdx.x;
  const int tx = t & 31, ty = t >> 5;
  const int rb = by*32, cb = bx*32;
  #pragma unroll
  for (int j = 0; j < 32; j += 8) tile[ty+j][tx] = in[(size_t)(rb+ty+j)*C + cb+tx];
  __syncthreads();
  #pragma unroll
  for (int j = 0; j < 32; j += 8) out[(size_t)(cb+ty+j)*R + rb+tx] = f2b(tile[tx][ty+j]);
}

// bf16 copy of fp32 input
__global__ __launch_bounds__(256)
void cvt_kernel(const float* __restrict__ in, ushort_t* __restrict__ out)
{
  const size_t base = ((size_t)blockIdx.x*256 + threadIdx.x)*4;
  ushort4v o4;
  #pragma unroll
  for (int j = 0; j < 4; j++) o4[j] = f2b(in[base + j]);
  *(ushort4v*)(out + base) = o4;
}

extern "C" void kernel_launch(void* const* d_in, const int* in_sizes, int n_in,
                              void* d_out, int out_size, void* d_ws, size_t ws_size,
                              hipStream_t stream)
{
  const float* x_in = (const float*)d_in[0];
  const float* Wq   = (const float*)d_in[1];
  const float* bq   = (const float*)d_in[2];
  const float* Wk   = (const float*)d_in[3];
  const float* bk   = (const float*)d_in[4];
  const float* Wv   = (const float*)d_in[5];
  const float* bv   = (const float*)d_in[6];
  const float* Wo   = (const float*)d_in[7];
  const float* bo   = (const float*)d_in[8];
  const float* ln1s = (const float*)d_in[9];
  const float* ln1b = (const float*)d_in[10];
  const float* W1   = (const float*)d_in[11];
  const float* b1   = (const float*)d_in[12];
  const float* W2   = (const float*)d_in[13];
  const float* b2   = (const float*)d_in[14];
  const float* ln2s = (const float*)d_in[15];
  const float* ln2b = (const float*)d_in[16];

  float* xf = (float*)d_out;            // fp32 master activation (also final output)

  char* ws = (char*)d_ws;
  const size_t MB = 1024*1024;
  ushort_t* xb     = (ushort_t*)(ws);              // 32MB bf16 activation
  char*     regB   = ws + 32*MB;                   // 160MB aliased region
  ushort_t* bufQ   = (ushort_t*)(regB);            // attn: 32MB Q -> V_attn
  ushort_t* bufK   = (ushort_t*)(regB + 32*MB);    // attn: 32MB K
  ushort_t* bufVal = (ushort_t*)(regB + 64*MB);    // attn: 32MB value -> pre-LN y
  ushort_t* bufH   = (ushort_t*)(regB);            // ff:   128MB hidden (stomps Q/K/Val)
  ushort_t* bufY   = (ushort_t*)(regB + 128*MB);   // ff:   32MB pre-LN y
  ushort_t* WqkvT  = (ushort_t*)(ws + 192*MB);     // 6MB [3072][1024]
  ushort_t* WoT    = (ushort_t*)(ws + 198*MB);     // 2MB
  ushort_t* W1T    = (ushort_t*)(ws + 200*MB);     // 8MB [4096][1024]
  ushort_t* W2T    = (ushort_t*)(ws + 208*MB);     // 8MB [1024][4096]
  float*    KV     = (float*)(ws + 216*MB);        // 16KB
  float*    Ksum   = (float*)(ws + 216*MB + 16*1024);

  const int M = 16384, D = 1024, FF = 4096;
  const dim3 blk(256);

  hipMemcpyAsync(xf, x_in, (size_t)M*D*sizeof(float), hipMemcpyDeviceToDevice, stream);
  cvt_kernel<<<dim3(M*D/1024), blk, 0, stream>>>(x_in, xb);

  for (int i = 0; i < 8; i++){
    TParams tp;
    tp.src[0] = Wq + (size_t)i*D*D;  tp.dst[0] = WqkvT;
    tp.src[1] = Wk + (size_t)i*D*D;  tp.dst[1] = WqkvT + 1024*1024;
    tp.src[2] = Wv + (size_t)i*D*D;  tp.dst[2] = WqkvT + 2*1024*1024;
    tp.src[3] = Wo + (size_t)i*D*D;  tp.dst[3] = WoT;
    tp.src[4] = W1 + (size_t)i*D*FF; tp.dst[4] = W1T;
    tp.src[5] = W2 + (size_t)i*FF*D; tp.dst[5] = W2T;
    transpose_all_kernel<<<dim3(12288), blk, 0, stream>>>(tp);

    // Q = elu(x@Wq+bq)+1 ; K = elu(x@Wk+bk)+1 ; value = x@Wv+bv  (one fused GEMM)
    qkv_gemm_kernel<<<dim3(128, 24), blk, 0, stream>>>(xb, WqkvT, bq + i*D, bk + i*D, bv + i*D,
                                                       bufQ, bufK, bufVal, D);

    hipMemsetAsync(KV, 0, 32*1024, stream);
    reduce_kv_kernel<<<dim3(256), blk, 0, stream>>>(bufK, bufVal, KV, Ksum);
    attn_map_kernel<<<dim3(16384), blk, 0, stream>>>(bufQ, KV, Ksum);

    // y = gelu(V_attn@Wo + bo) + x ; x = LN1(y)
    gemm_kernel<3><<<dim3(128, 8), blk, 0, stream>>>(bufQ, WoT, bo + i*D, xf, bufVal, D, D);
    ln_kernel<<<dim3(16384), blk, 0, stream>>>(bufVal, ln1s + i*D, ln1b + i*D, xb, xf);

    // h = gelu(x@W1 + b1) ; y = gelu(h@W2 + b2) + x ; x = LN2(y)   (full M)
    gemm_kernel<2><<<dim3(128, 32), blk, 0, stream>>>(xb, W1T, b1 + i*FF, nullptr, bufH, FF, D);
    gemm_kernel<3><<<dim3(128, 8),  blk, 0, stream>>>(bufH, W2T, b2 + i*D, xf, bufY, D, FF);
    ln_kernel<<<dim3(16384), blk, 0, stream>>>(bufY, ln2s + i*D, ln2b + i*D, xb, xf);
  }
  (void)in_sizes; (void)n_in; (void)out_size; (void)ws_size;
}